// Round 5
// baseline (246.186 us; speedup 1.0000x reference)
//
#include <hip/hip_runtime.h>

// ROIAlign3d: x=[2,256,16,64,64] f32, rois=[64,5] -> out=[64,256,16,7,7] f32.
// R6: block = (roi, c-pair) -> 32 (c,t) planes staged as exact boxes in LDS,
// plane stride PS = nrows*rowst+1 (ODD -> lane*PS mod 32 is a permutation ->
// tap reads are bank-conflict-free). Phase B: lane = plane (half-wave of 32),
// bin uniform per half-wave -> sample table reads are broadcasts and all
// per-sample VALU is shared; each lane does only 16 FMAs + 8 paired LDS
// reads per bin. Sample table (196 entries) built once per block.
// Staging: scalar-dword, lane-consecutive (conflict-free LDS writes,
// coalesced global row runs). 512 thr, LDS 48.4KB -> 3 blocks/CU (24 waves).

__global__ __launch_bounds__(512) void roialign3d_kernel(
    const float* __restrict__ x, const float* __restrict__ rois,
    float* __restrict__ out)
{
    constexpr int C = 256, T = 16, H = 64, W = 64;
    constexpr float SCALE = 0.0625f;
    constexpr int TOT = 2 * C * T * H * W;   // 33,554,432 elements
    constexpr int P = 32;                    // planes per block (2c x 16t)
    constexpr int MAXD  = 17 * 20;           // worst box dwords per plane
    constexpr int MAXPS = MAXD + 1;          // 341 (odd)

    __shared__ float  s_box[P * MAXPS];      // 43,648 B
    __shared__ int2   s_off[4 * 49];         //  1,568 B
    __shared__ float4 s_wt[4 * 49];          //  3,136 B

    const int b   = blockIdx.x;
    const int r   = b & 63;                  // roi-inner: same-batch rois
    const int cp  = b >> 6;                  // share planes in L2
    const int c0  = cp << 1;
    const int tid = threadIdx.x;

    // ---- uniform roi params ----
    const float r1 = rois[r * 5 + 1], r2 = rois[r * 5 + 2];
    const float r3 = rois[r * 5 + 3], r4 = rois[r * 5 + 4];
    const int   bidx = (int)rois[r * 5 + 0];

    const float sw_ = r1 * SCALE, sh_ = r2 * SCALE;
    const float ew_ = r3 * SCALE, eh_ = r4 * SCALE;
    const float bin_w = fmaxf(ew_ - sw_, 1.0f) * (1.0f / 7.0f);
    const float bin_h = fmaxf(eh_ - sh_, 1.0f) * (1.0f / 7.0f);

    // exact sampled extents (monotone; first sample +0.25*bin, last +6.75)
    const float ys_min = sh_ + 0.25f * bin_h, ys_max = sh_ + 6.75f * bin_h;
    const float xs_min = sw_ + 0.25f * bin_w, xs_max = sw_ + 6.75f * bin_w;
    const int y_lo  = (int)floorf(fminf(fmaxf(ys_min, 0.0f), (float)(H - 1)));
    const int y0mx  = (int)floorf(fminf(fmaxf(ys_max, 0.0f), (float)(H - 1)));
    const int x_lo  = (int)floorf(fminf(fmaxf(xs_min, 0.0f), (float)(W - 1)));
    const int x0mx  = (int)floorf(fminf(fmaxf(xs_max, 0.0f), (float)(W - 1)));
    const int x4_lo = x_lo & ~3;

    const int nrows = min(y0mx + 1, H - 1) - y_lo + 1;   // <= 17
    const int ncol4 = ((x0mx + 1 - x4_lo) >> 2) + 1;     // <= 5
    const int rowst = ncol4 << 2;                        // dwords per row
    const int D     = nrows * rowst;                     // box dwords (even)
    const int PS    = D + 1;                             // odd plane stride

    // ---- sample table: 196 entries ----
    if (tid < 4 * 49) {
        const int s  = tid / 49;
        const int pp = tid - s * 49;
        const int ph = pp / 7, pw = pp - ph * 7;
        const float gyf = ((float)(s >> 1) + 0.5f) * 0.5f;
        const float gxf = ((float)(s & 1) + 0.5f) * 0.5f;

        const float ys = sh_ + ((float)ph + gyf) * bin_h;
        const float xs = sw_ + ((float)pw + gxf) * bin_w;

        const bool vy = (ys >= -1.0f) && (ys <= (float)H);
        const bool vx = (xs >= -1.0f) && (xs <= (float)W);

        const float yc = fminf(fmaxf(ys, 0.0f), (float)(H - 1));
        const int   y0 = (int)floorf(yc);
        const float ly = yc - (float)y0, hy = 1.0f - ly;
        const int   y1 = min(y0 + 1, H - 1);

        const float xc = fminf(fmaxf(xs, 0.0f), (float)(W - 1));
        const int   x0 = (int)floorf(xc);
        const float lx = xc - (float)x0, hx = 1.0f - lx;
        const bool  xpair = (x0 < W - 1);

        const float wxh = xpair ? hx : (hx + lx);   // fold x-clamp into x0
        const float wxl = xpair ? lx : 0.0f;
        const float m   = (vy && vx) ? 0.25f : 0.0f;

        const int relc = x0 - x4_lo;                // 0..18
        s_off[tid] = make_int2((y0 - y_lo) * rowst + relc,
                               (y1 - y_lo) * rowst + relc);
        s_wt[tid]  = make_float4(hy * wxh * m, hy * wxl * m,
                                 ly * wxh * m, ly * wxl * m);
    }

    // ---- stage exact boxes, scalar dwords, lane-consecutive ----
    {
        const int total = P * D;                          // <= 10,880
        const unsigned inv_D  = (1u << 22) / (unsigned)D + 1u;     // exact: i*e < 32*D*D <= 3.7M < 2^22
        const unsigned inv_rs = 65536u / (unsigned)rowst + 1u;     // exact: rem*e <= 339*20 < 2^16
        const int pb0 = (bidx * C + c0) * T;              // plane0 index
        for (int i = tid; i < total; i += 512) {
            const int p   = (int)(((unsigned)i * inv_D) >> 22);
            const int rem = i - p * D;
            const int row = (int)(((unsigned)rem * inv_rs) >> 16);
            const int col = rem - row * rowst;            // dword col
            const int pli = pb0 + ((p >> 4) << 4 /* c step = 16 t-planes */) + (p & 15);
            int sidx = (pli << 12) + ((y_lo + row) << 6) + x4_lo + col;
            sidx = min(sidx, TOT - 1);                    // array-end guard
            s_box[p * PS + rem] = x[sidx];
        }
    }
    __syncthreads();

    // ---- Phase B: lane = plane, bin uniform per half-wave ----
    const int l  = tid & 63;
    const int w  = tid >> 6;          // 0..7
    const int hh = l >> 5;            // half-wave
    const int pl = l & 31;            // plane 0..31
    const float* __restrict__ bx = &s_box[pl * PS];
    const int c = c0 + (pl >> 4);
    const int t = pl & 15;
    float* __restrict__ op = out + (size_t)(((r * C + c) * T + t) * 49);

    for (int q = w; q < 25; q += 8) {
        const int bin = 2 * q + hh;
        if (bin < 49) {
            float acc = 0.0f;
#pragma unroll
            for (int s = 0; s < 4; ++s) {
                const int2   o  = s_off[s * 49 + bin];
                const float4 wt = s_wt[s * 49 + bin];
                acc += wt.x * bx[o.x] + wt.y * bx[o.x + 1] +
                       wt.z * bx[o.y] + wt.w * bx[o.y + 1];
            }
            op[bin] = acc;
        }
    }
}

extern "C" void kernel_launch(void* const* d_in, const int* in_sizes, int n_in,
                              void* d_out, int out_size, void* d_ws, size_t ws_size,
                              hipStream_t stream) {
    const float* x    = (const float*)d_in[0];
    const float* rois = (const float*)d_in[1];
    float* out = (float*)d_out;

    // 64 rois * 128 c-pairs = 8192 blocks, roi-inner
    roialign3d_kernel<<<dim3(8192), dim3(512), 0, stream>>>(x, rois, out);
}

// Round 6
// 217.837 us; speedup vs baseline: 1.1301x; 1.1301x over previous
//
#include <hip/hip_runtime.h>

// ROIAlign3d: x=[2,256,16,64,64] f32, rois=[64,5] -> out=[64,256,16,7,7] f32.
// R7: R4 skeleton (P=8 exact-box float4 staging, 32768 blocks roi-inner,
// 15.6KB LDS -> 8 blocks/CU) + R6's conflict-free Phase B grafted on:
// LDS plane stride PS4 = nrc4|1 float4s (odd -> pl*4*PS4 mod 32 is a
// permutation -> 8 planes on 8 distinct banks); Phase B lane=plane within
// 8-lane groups, bin uniform per group -> table reads are broadcasts at
// consecutive addresses (conflict-free) and tap reads are group-uniform
// offsets across distinct banks. Staging stays 16B-aligned float4.

#define NBINS 49
#define NSAMP 4
#define P     8             // t-planes per block (half of T)
#define MAXB4 85            // max float4 per plane box (17 rows x 5)

__global__ __launch_bounds__(256) void roialign3d_kernel(
    const float* __restrict__ x, const float* __restrict__ rois,
    float* __restrict__ out)
{
    constexpr int C = 256, T = 16, H = 64, W = 64;
    constexpr float SCALE = 0.0625f;
    constexpr int TOT = 2 * C * T * H * W;   // 33,554,432 elements

    __shared__ float4 s_box4[P * MAXB4];     // 10,880 B
    __shared__ int2   s_off[NSAMP * NBINS];  //  1,568 B
    __shared__ float4 s_wt[NSAMP * NBINS];   //  3,136 B

    const int b   = blockIdx.x;
    const int c   = b >> 7;          // channel outer
    const int rg  = b & 127;         // roi inner -> cross-roi L2 reuse
    const int r   = rg >> 1;
    const int g   = rg & 1;          // which half of T
    const int tid = threadIdx.x;

    // ---- uniform roi params ----
    const float r1 = rois[r * 5 + 1], r2 = rois[r * 5 + 2];
    const float r3 = rois[r * 5 + 3], r4 = rois[r * 5 + 4];
    const int   bidx = (int)rois[r * 5 + 0];

    const float sw_ = r1 * SCALE, sh_ = r2 * SCALE;
    const float ew_ = r3 * SCALE, eh_ = r4 * SCALE;
    const float bin_w = fmaxf(ew_ - sw_, 1.0f) * (1.0f / 7.0f);
    const float bin_h = fmaxf(eh_ - sh_, 1.0f) * (1.0f / 7.0f);

    // exact sampled extents (monotone; first sample +0.25*bin, last +6.75)
    const float ys_min = sh_ + 0.25f * bin_h, ys_max = sh_ + 6.75f * bin_h;
    const float xs_min = sw_ + 0.25f * bin_w, xs_max = sw_ + 6.75f * bin_w;
    const int y_lo  = (int)floorf(fminf(fmaxf(ys_min, 0.0f), (float)(H - 1)));
    const int y0mx  = (int)floorf(fminf(fmaxf(ys_max, 0.0f), (float)(H - 1)));
    const int x_lo  = (int)floorf(fminf(fmaxf(xs_min, 0.0f), (float)(W - 1)));
    const int x0mx  = (int)floorf(fminf(fmaxf(xs_max, 0.0f), (float)(W - 1)));
    const int x4_lo = x_lo & ~3;

    const int nrows = min(y0mx + 1, H - 1) - y_lo + 1;   // <= 17
    const int ncol4 = ((x0mx + 1 - x4_lo) >> 2) + 1;     // <= 5
    const int rowst = ncol4 << 2;                        // dwords per row
    const int nrc4  = nrows * ncol4;                     // float4 per plane
    const int PS4   = nrc4 | 1;                          // odd plane stride

    // ---- sample table: 196 entries (threads 196..255 fall through) ----
    if (tid < NSAMP * NBINS) {
        const int s  = tid / NBINS;
        const int pp = tid - s * NBINS;
        const int ph = pp / 7, pw = pp - ph * 7;
        const float gyf = ((float)(s >> 1) + 0.5f) * 0.5f;
        const float gxf = ((float)(s & 1) + 0.5f) * 0.5f;

        const float ys = sh_ + ((float)ph + gyf) * bin_h;
        const float xs = sw_ + ((float)pw + gxf) * bin_w;

        const bool vy = (ys >= -1.0f) && (ys <= (float)H);
        const bool vx = (xs >= -1.0f) && (xs <= (float)W);

        const float yc = fminf(fmaxf(ys, 0.0f), (float)(H - 1));
        const int   y0 = (int)floorf(yc);
        const float ly = yc - (float)y0, hy = 1.0f - ly;
        const int   y1 = min(y0 + 1, H - 1);

        const float xc = fminf(fmaxf(xs, 0.0f), (float)(W - 1));
        const int   x0 = (int)floorf(xc);
        const float lx = xc - (float)x0, hx = 1.0f - lx;
        const bool  xpair = (x0 < W - 1);

        const float wxh = xpair ? hx : (hx + lx);   // fold x-clamp into x0
        const float wxl = xpair ? lx : 0.0f;
        const float m   = (vy && vx) ? 0.25f : 0.0f;

        const int relc = x0 - x4_lo;                // 0..18
        s_off[tid] = make_int2((y0 - y_lo) * rowst + relc,
                               (y1 - y_lo) * rowst + relc);
        s_wt[tid]  = make_float4(hy * wxh * m, hy * wxl * m,
                                 ly * wxh * m, ly * wxl * m);
    }

    // ---- stage exact box for 8 planes: nrc4 float4 each, coalesced ----
    {
        const int total = P * nrc4;                 // <= 680
        const unsigned inv_nrc = 65535u / (unsigned)nrc4  + 1u;  // exact i<680
        const unsigned inv_c   = 65535u / (unsigned)ncol4 + 1u;  // exact rem<85
        const int pbase = ((bidx * C + c) * T + (g << 3)) << 12; // elem (c,t0)
        for (int i = tid; i < total; i += 256) {    // ~2 iters typical
            const int p   = (int)(((unsigned)i * inv_nrc) >> 16);
            const int rem = i - p * nrc4;
            const int row = (int)(((unsigned)rem * inv_c) >> 16);
            const int col = rem - row * ncol4;
            int sidx = pbase + (p << 12) + ((y_lo + row) << 6) + x4_lo + (col << 2);
            sidx = min(sidx, TOT - 4);              // array-end guard
            s_box4[p * PS4 + rem] = *(const float4*)(x + sidx);
        }
    }
    __syncthreads();

    // ---- Phase B: lane = plane (8-lane groups), bin uniform per group ----
    const int l    = tid & 63;
    const int w    = tid >> 6;          // wave 0..3
    const int pl   = l & 7;             // plane 0..7
    const int grp  = l >> 3;            // 0..7
    const int slot = (w << 3) + grp;    // 0..31
    const float* __restrict__ bx = (const float*)s_box4 + pl * (PS4 << 2);
    const int t = (g << 3) + pl;
    float* __restrict__ op = out + (size_t)(((r * C + c) * T + t) * NBINS);

    for (int bin = slot; bin < NBINS; bin += 32) {  // 1..2 bins per lane
        float acc = 0.0f;
#pragma unroll
        for (int s = 0; s < NSAMP; ++s) {
            const int2   o  = s_off[s * NBINS + bin];
            const float4 wt = s_wt[s * NBINS + bin];
            acc += wt.x * bx[o.x] + wt.y * bx[o.x + 1] +
                   wt.z * bx[o.y] + wt.w * bx[o.y + 1];
        }
        op[bin] = acc;
    }
}

extern "C" void kernel_launch(void* const* d_in, const int* in_sizes, int n_in,
                              void* d_out, int out_size, void* d_ws, size_t ws_size,
                              hipStream_t stream) {
    const float* x    = (const float*)d_in[0];
    const float* rois = (const float*)d_in[1];
    float* out = (float*)d_out;

    // 64 rois * 256 channels * 2 t-halves = 32768 blocks, roi-inner
    roialign3d_kernel<<<dim3(32768), dim3(256), 0, stream>>>(x, rois, out);
}